// Round 18
// baseline (81.820 us; speedup 1.0000x reference)
//
#include <hip/hip_runtime.h>
#include <stdint.h>

#define MARGIN 0.3f
#define NROWS 4096
#define DIM   2048
#define ROWB  1024                  // fp4: DIM/2 bytes per row
#define BT    128
#define BKB   128                   // bytes per row per K-step (256 elements)
#define NKS   (ROWB / BKB)          // 8 K-steps
#define NB    (NROWS / BT)          // 32
#define NBLK  (NB * (NB + 1) / 2)   // 528
#define NBLK4 (NBLK * 4)            // 2112 one-wave quadrant blocks (%8==0)

typedef float f32x4 __attribute__((ext_vector_type(4)));
typedef int   i32x4 __attribute__((ext_vector_type(4)));
typedef int   i32x8 __attribute__((ext_vector_type(8)));
typedef short s16x8 __attribute__((ext_vector_type(8)));

__device__ __forceinline__ ushort f32_to_bf16(float f) {
  uint32_t u = __float_as_uint(f);
  return (ushort)((u + 0x7FFFu + ((u >> 16) & 1u)) >> 16);
}

// e2m1 quantizer, RNE to grid {0,.5,1,1.5,2,3,4,6}, clamp at 6.
__device__ __forceinline__ unsigned f32_to_fp4(float y) {
  unsigned s = (__float_as_uint(y) >> 31) << 3;
  float a = fabsf(y);
  unsigned c;
  if      (a < 0.25f) c = 0;
  else if (a < 0.75f) c = 1;
  else if (a < 1.25f) c = 2;
  else if (a < 1.75f) c = 3;
  else if (a < 2.5f)  c = 4;
  else if (a < 3.5f)  c = 5;
  else if (a < 5.0f)  c = 6;
  else                c = 7;
  return s | c;
}

// async global->LDS, 16B per lane. LDS dest is wave-uniform base + lane*16
// (linear). Swizzle is carried on the GLOBAL source address.
__device__ __forceinline__ void async_load16(const void* g, void* l) {
  __builtin_amdgcn_global_load_lds(
      (const __attribute__((address_space(1))) uint32_t*)g,
      (__attribute__((address_space(3))) uint32_t*)l, 16, 0, 0);
}

// ---------------------------------------------------------------------------
// prep (R10 verbatim, measured fast): row L2-norm -> normalized fp4(e2m1)
// row-major matrix at scale 2^6 (undone by the MFMA scale operand).
// Zeroes the accumulators.
// ---------------------------------------------------------------------------
__global__ __launch_bounds__(256) void prep_kernel(const float* __restrict__ in,
                                                   unsigned char* __restrict__ pn,
                                                   float* __restrict__ accum) {
  const int row = blockIdx.x;
  const int tid = threadIdx.x;
  if (row == 0 && tid == 0) { accum[0] = 0.f; accum[1] = 0.f; }

  const float4* rp = (const float4*)(in + (size_t)row * DIM);
  float4 v0 = rp[tid * 2];
  float4 v1 = rp[tid * 2 + 1];
  float ss = v0.x*v0.x + v0.y*v0.y + v0.z*v0.z + v0.w*v0.w
           + v1.x*v1.x + v1.y*v1.y + v1.z*v1.z + v1.w*v1.w;
  #pragma unroll
  for (int off = 32; off; off >>= 1) ss += __shfl_down(ss, off);

  __shared__ float wred[4];
  __shared__ float stot;
  const int lane = tid & 63, w = tid >> 6;
  if (lane == 0) wred[w] = ss;
  __syncthreads();
  if (tid == 0) stot = wred[0] + wred[1] + wred[2] + wred[3];
  __syncthreads();
  const float inv = 1.0f / fmaxf(sqrtf(stot), 1e-12f);

  const float sc = inv * 64.0f;            // pre-scale by 2^6
  float e[8] = {v0.x, v0.y, v0.z, v0.w, v1.x, v1.y, v1.z, v1.w};
  uint32_t u = 0;
  #pragma unroll
  for (int j = 0; j < 4; ++j) {
    unsigned lo = f32_to_fp4(e[2*j]   * sc);
    unsigned hi = f32_to_fp4(e[2*j+1] * sc);
    u |= (lo | (hi << 4)) << (8 * j);
  }
  *(uint32_t*)(pn + (size_t)row * ROWB + tid * 4) = u;
}

// ---------------------------------------------------------------------------
// tri_gemm: ONE WAVE PER BLOCK, one 64x64 quadrant of an upper-tri 128x128
// tile -> 2112 blocks, 16 KB LDS each => ~8 CO-RESIDENT INDEPENDENT blocks
// per CU (LDS limit 10, wave limit 32). Rationale: every prior LDS round had
// 2 big lockstep blocks/CU, so each K-step's vmcnt(0) drain (~700cy,
// L3-resident) sat exposed; 8 independent stage->drain->compute pipelines
// per CU overlap each other (m114). Per-block machinery is R10 verbatim:
// fp4 e2m1 via mfma_scale_f32_16x16x128_f8f6f4 (cbsz=blgp=4, scale 0x79 =
// 2^-6 -> acc = sim), BKB=128B/row/step (8 steps), 8-slot x 16B rows with
// the verified slot XOR (slot ^ (row&7)) -> conflict-free ds_read_b128,
// global_load_lds staging with the swizzle on the GLOBAL source address.
// ---------------------------------------------------------------------------
__global__ __launch_bounds__(64) void tri_gemm(const unsigned char* __restrict__ pn,
                                               float* __restrict__ accum) {
  // XCD-aware bijective swizzle (NBLK4 % 8 == 0); consecutive swz values =
  // quadrants of the same tile -> per-XCD L2 locality.
  const int b   = blockIdx.x;
  const int swz = (b & 7) * (NBLK4 / 8) + (b >> 3);
  int t = swz >> 2;
  const int q = swz & 3;
  int bi = 0;
  while (t >= NB - bi) { t -= NB - bi; ++bi; }
  const int bj = bi + t;
  const int wr = q >> 1, wc = q & 1;

  __shared__ __align__(16) unsigned char Asm[64 * BKB];   // 8 KB
  __shared__ __align__(16) unsigned char Bsm[64 * BKB];   // 8 KB

  const int lane = threadIdx.x;
  const int fr   = lane & 15;         // fragment row within 16
  const int g    = lane >> 4;         // 16B k-group within 64B sub-K

  f32x4 acc[4][4] = {};
  const int rowA = bi * BT + wr * 64;
  const int rowB = bj * BT + wc * 64;

  // staging: 1 KB chunk = 8 rows x 128 B; lane l -> row +(l>>3), stored slot
  // (l&7); global true-k slot = (l&7) ^ (l>>3)   [row&7 == l>>3]
  const int srow  = (lane >> 3);
  const int gslot = (lane & 7) ^ srow;

  const unsigned char* gA = pn + (size_t)(rowA + srow) * ROWB + gslot * 16;
  const unsigned char* gB = pn + (size_t)(rowB + srow) * ROWB + gslot * 16;

  const i32x4 z4 = {0, 0, 0, 0};

  for (int ks = 0; ks < NKS; ++ks) {
    const int kb = ks * BKB;          // byte offset within source row
    if (ks) __syncthreads();          // prior reads done before overwrite
    #pragma unroll
    for (int c = 0; c < 8; ++c) {     // 8 chunks x (A,B) = 16 issues
      async_load16(gA + (size_t)(8 * c) * ROWB + kb, Asm + (8 * c) * BKB);
      async_load16(gB + (size_t)(8 * c) * ROWB + kb, Bsm + (8 * c) * BKB);
    }
    __syncthreads();                  // vmcnt(0) drain: data visible

    // sub-K kk covers true k-bytes [kk*64, kk*64+64); lane's 16B for kgroup g
    // sits at stored slot (kk*4 + g) ^ (row&7). One ds_read_b128 each.
    #pragma unroll
    for (int kk = 0; kk < 2; ++kk) {
      i32x8 af[4], bf[4];
      #pragma unroll
      for (int m = 0; m < 4; ++m) {
        const int ra = m * 16 + fr;
        i32x4 va = *(const i32x4*)(Asm + ra * BKB + (((kk * 4 + g) ^ (ra & 7)) * 16));
        af[m] = __builtin_shufflevector(va, z4, 0, 1, 2, 3, 4, 5, 6, 7);
        i32x4 vb = *(const i32x4*)(Bsm + ra * BKB + (((kk * 4 + g) ^ (ra & 7)) * 16));
        bf[m] = __builtin_shufflevector(vb, z4, 0, 1, 2, 3, 4, 5, 6, 7);
      }
      #pragma unroll
      for (int m = 0; m < 4; ++m)
        #pragma unroll
        for (int n = 0; n < 4; ++n)
          acc[m][n] = __builtin_amdgcn_mfma_scale_f32_16x16x128_f8f6f4(
              af[m], bf[n], acc[m][n],
              4, 4,                      // cbsz=fp4(e2m1), blgp=fp4(e2m1)
              0, 0x79797979,             // scale_a: e8m0 = 2^-6 everywhere
              0, 0x79797979);            // scale_b: e8m0 = 2^-6 everywhere
    }
  }

  // ---- epilogue: mask + wave reduce + 2 atomics ----
  float lsum = 0.f, lcnt = 0.f;
  #pragma unroll
  for (int m = 0; m < 4; ++m) {
    #pragma unroll
    for (int n = 0; n < 4; ++n) {
      #pragma unroll
      for (int r = 0; r < 4; ++r) {
        int gi = rowA + m * 16 + g * 4 + r;
        int gj = rowB + n * 16 + fr;
        float s = acc[m][n][r];
        if (gi < gj && s > MARGIN) { lsum += s - MARGIN; lcnt += 1.f; }
      }
    }
  }
  #pragma unroll
  for (int off = 32; off; off >>= 1) {
    lsum += __shfl_down(lsum, off);
    lcnt += __shfl_down(lcnt, off);
  }
  if (lane == 0) {
    atomicAdd(&accum[0], lsum);
    atomicAdd(&accum[1], lcnt);
  }
}

// ---------------------------------------------------------------------------
// Fallback (tiny workspace): bf16 on-the-fly convert (verified R2 structure).
// ---------------------------------------------------------------------------
__global__ __launch_bounds__(256) void prep_inv(const float* __restrict__ in,
                                                float* __restrict__ invn,
                                                float* __restrict__ accum) {
  const int row = blockIdx.x;
  const int tid = threadIdx.x;
  if (row == 0 && tid == 0) { accum[0] = 0.f; accum[1] = 0.f; }
  const float4* rp = (const float4*)(in + (size_t)row * DIM);
  float4 v0 = rp[tid * 2];
  float4 v1 = rp[tid * 2 + 1];
  float ss = v0.x*v0.x + v0.y*v0.y + v0.z*v0.z + v0.w*v0.w
           + v1.x*v1.x + v1.y*v1.y + v1.z*v1.z + v1.w*v1.w;
  #pragma unroll
  for (int off = 32; off; off >>= 1) ss += __shfl_down(ss, off);
  __shared__ float wred[4];
  const int lane = tid & 63, w = tid >> 6;
  if (lane == 0) wred[w] = ss;
  __syncthreads();
  if (tid == 0)
    invn[row] = 1.0f / fmaxf(sqrtf(wred[0] + wred[1] + wred[2] + wred[3]), 1e-12f);
}

__global__ __launch_bounds__(256) void tri_gemm_fly(const float* __restrict__ inF,
                                                    const float* __restrict__ invn,
                                                    float* __restrict__ accum) {
  enum { FBK = 64 };
  int t = blockIdx.x, bi = 0;
  while (t >= NB - bi) { t -= NB - bi; ++bi; }
  const int bj = bi + t;

  __shared__ __align__(16) ushort Asm[BT * FBK];
  __shared__ __align__(16) ushort Bsm[BT * FBK];

  const int tid  = threadIdx.x;
  const int lane = tid & 63;
  const int w    = tid >> 6;
  const int wr   = w >> 1, wc = w & 1;

  f32x4 acc[4][4] = {};
  const int rowA = bi * BT, rowB = bj * BT;

  for (int k0 = 0; k0 < DIM; k0 += FBK) {
    if (k0) __syncthreads();
    #pragma unroll
    for (int p = 0; p < 8; ++p) {
      int c   = p * 256 + tid;
      int isB = c >> 10;
      int cc  = c & 1023;
      int r   = cc >> 3;
      int s   = cc & 7;
      const int grow = (isB ? rowB : rowA) + r;
      const float4* src = (const float4*)(inF + (size_t)grow * DIM + k0 + s * 8);
      float4 v0 = src[0], v1 = src[1];
      int4 pack;
      ushort* h = (ushort*)&pack;
      h[0] = f32_to_bf16(v0.x); h[1] = f32_to_bf16(v0.y);
      h[2] = f32_to_bf16(v0.z); h[3] = f32_to_bf16(v0.w);
      h[4] = f32_to_bf16(v1.x); h[5] = f32_to_bf16(v1.y);
      h[6] = f32_to_bf16(v1.z); h[7] = f32_to_bf16(v1.w);
      *(int4*)((isB ? Bsm : Asm) + r * FBK + (s ^ (r & 7)) * 8) = pack;
    }
    __syncthreads();

    s16x8 af[2][4], bfv[2][4];
    const int fr = lane & 15, hi = lane >> 4;
    #pragma unroll
    for (int kk = 0; kk < 2; ++kk)
      #pragma unroll
      for (int m = 0; m < 4; ++m) {
        const int ra = wr * 64 + m * 16 + fr;
        af[kk][m] = *(const s16x8*)(Asm + ra * FBK + ((kk * 4 + hi) ^ (ra & 7)) * 8);
        const int rb = wc * 64 + m * 16 + fr;
        bfv[kk][m] = *(const s16x8*)(Bsm + rb * FBK + ((kk * 4 + hi) ^ (rb & 7)) * 8);
      }
    #pragma unroll
    for (int kk = 0; kk < 2; ++kk)
      #pragma unroll
      for (int m = 0; m < 4; ++m)
        #pragma unroll
        for (int n = 0; n < 4; ++n)
          acc[m][n] = __builtin_amdgcn_mfma_f32_16x16x32_bf16(af[kk][m], bfv[kk][n],
                                                              acc[m][n], 0, 0, 0);
  }

  float lsum = 0.f, lcnt = 0.f;
  const int gib = rowA + wr * 64;
  const int gjb = rowB + wc * 64;
  #pragma unroll
  for (int m = 0; m < 4; ++m)
    #pragma unroll
    for (int n = 0; n < 4; ++n)
      #pragma unroll
      for (int r = 0; r < 4; ++r) {
        int gi = gib + m * 16 + (lane >> 4) * 4 + r;
        int gj = gjb + n * 16 + (lane & 15);
        float s = acc[m][n][r] * invn[gi] * invn[gj];
        if (gi < gj && s > MARGIN) { lsum += s - MARGIN; lcnt += 1.f; }
      }
  #pragma unroll
  for (int off = 32; off; off >>= 1) {
    lsum += __shfl_down(lsum, off);
    lcnt += __shfl_down(lcnt, off);
  }
  __shared__ float rs[4], rc[4];
  if (lane == 0) { rs[w] = lsum; rc[w] = lcnt; }
  __syncthreads();
  if (tid == 0) {
    atomicAdd(&accum[0], rs[0] + rs[1] + rs[2] + rs[3]);
    atomicAdd(&accum[1], rc[0] + rc[1] + rc[2] + rc[3]);
  }
}

__global__ void finalize_kernel(const float* __restrict__ accum, float* __restrict__ out) {
  if (threadIdx.x == 0) out[0] = (accum[1] < 0.5f) ? 0.0f : accum[0] / accum[1];
}

extern "C" void kernel_launch(void* const* d_in, const int* in_sizes, int n_in,
                              void* d_out, int out_size, void* d_ws, size_t ws_size,
                              hipStream_t stream) {
  const float* in = (const float*)d_in[0];
  float* out = (float*)d_out;
  const size_t pn_bytes = (size_t)NROWS * ROWB;   // fp4: 4.2 MB

  if (ws_size >= pn_bytes + 2 * sizeof(float)) {
    unsigned char* pn = (unsigned char*)d_ws;
    float* accum = (float*)((char*)d_ws + pn_bytes);
    prep_kernel<<<NROWS, 256, 0, stream>>>(in, pn, accum);
    tri_gemm<<<NBLK4, 64, 0, stream>>>(pn, accum);
    finalize_kernel<<<1, 64, 0, stream>>>(accum, out);
  } else {
    float* invn  = (float*)d_ws;
    float* accum = (float*)((char*)d_ws + NROWS * sizeof(float));
    prep_inv<<<NROWS, 256, 0, stream>>>(in, invn, accum);
    tri_gemm_fly<<<NBLK, 256, 0, stream>>>(in, invn, accum);
    finalize_kernel<<<1, 64, 0, stream>>>(accum, out);
  }
}